// Round 1
// baseline (769.010 us; speedup 1.0000x reference)
//
#include <hip/hip_runtime.h>

// ---------------------------------------------------------------------------
// SelfAttention forward (N=2, L=2048, E=1024, H=16, D=64), f32 in/out.
// Outputs concatenated: out | q | k | v | energy | attention
// Strategy: bf16 MFMA (16x16x32) for all GEMM-shaped work; f32 softmax.
// Scratch plan: dead d_out regions host bf16 temporaries (energy region for
// bf16 inputs/weights, attention region for bf16 q/k, out region for v^T);
// d_ws holds only head_out bf16 (8MB) + Wo bf16 (2MB) = 10.5 MB.
// ---------------------------------------------------------------------------

typedef __attribute__((ext_vector_type(8))) short     s16x8;   // 8 bf16 (4 VGPR)
typedef __attribute__((ext_vector_type(4))) float     f32x4;
typedef __attribute__((ext_vector_type(8))) unsigned short u16x8;
typedef __attribute__((ext_vector_type(4))) unsigned short u16x4;

#define DEVINL __device__ __forceinline__

DEVINL unsigned short f2b(float f) {           // f32 -> bf16 (RNE)
  unsigned int u = __builtin_bit_cast(unsigned int, f);
  u = (u + 0x7FFFu + ((u >> 16) & 1u)) >> 16;
  return (unsigned short)u;
}

DEVINL s16x8 pack8(float4 a, float4 b) {
  s16x8 r;
  r[0] = (short)f2b(a.x); r[1] = (short)f2b(a.y);
  r[2] = (short)f2b(a.z); r[3] = (short)f2b(a.w);
  r[4] = (short)f2b(b.x); r[5] = (short)f2b(b.y);
  r[6] = (short)f2b(b.z); r[7] = (short)f2b(b.w);
  return r;
}

DEVINL f32x4 mfma16(s16x8 a, s16x8 b, f32x4 c) {
  return __builtin_amdgcn_mfma_f32_16x16x32_bf16(a, b, c, 0, 0, 0);
}

// ---------------------------------------------------------------------------
// f32 -> bf16 bulk convert
// ---------------------------------------------------------------------------
__global__ __launch_bounds__(256) void f32_to_bf16_k(
    const float* __restrict__ s, unsigned short* __restrict__ d, int n) {
  int i = (blockIdx.x * 256 + threadIdx.x) * 4;
  if (i < n) {
    float4 v = *(const float4*)(s + i);
    u16x4 o;
    o[0] = f2b(v.x); o[1] = f2b(v.y); o[2] = f2b(v.z); o[3] = f2b(v.w);
    *(u16x4*)(d + i) = o;
  }
}

// ---------------------------------------------------------------------------
// Generic NT GEMM:  C[m][n] = sum_k A[m][k] * B[n][k]  (+ bias[n])
// A: (M x K) bf16 row-major (lda elems), B: (N x K) bf16 row-major (ldb).
// Block tile 64(M) x 128(N); 4 waves, wave tile 32x64; MFMA 16x16x32 bf16.
// blockIdx.x = N tile, blockIdx.y = M tile, blockIdx.z = (n*16+h) batch with
// separate n/h strides (projections pass all-zero strides, grid z=1).
// ---------------------------------------------------------------------------
template<bool BIAS, bool WF32, bool WB16>
__global__ __launch_bounds__(256) void gemm_nt(
    const unsigned short* __restrict__ A, long long lda, long long sAn, long long sAh,
    const unsigned short* __restrict__ B, long long ldb, long long sBn, long long sBh,
    const float* __restrict__ bias,
    float* __restrict__ Cf, unsigned short* __restrict__ Cb,
    long long ldc, long long sCz, int K) {
  int z = blockIdx.z, zn = z >> 4, zh = z & 15;
  A += (size_t)zn * sAn + (size_t)zh * sAh;
  B += (size_t)zn * sBn + (size_t)zh * sBh;
  size_t coff = (size_t)z * (size_t)sCz;

  int t = threadIdx.x, lane = t & 63, w = t >> 6;
  int wm = (w >> 1) * 32, wn = (w & 1) * 64;
  int m0 = blockIdx.y * 64 + wm;
  int n0 = blockIdx.x * 128 + wn;
  int lr = lane & 15, kg = (lane >> 4) * 8;

  f32x4 acc[2][4] = {};
  const unsigned short* Ap = A + (size_t)(m0 + lr) * lda + kg;
  const unsigned short* Bp = B + (size_t)(n0 + lr) * ldb + kg;

  for (int k0 = 0; k0 < K; k0 += 32) {
    s16x8 af0 = *(const s16x8*)(Ap);
    s16x8 af1 = *(const s16x8*)(Ap + 16 * lda);
    s16x8 bf0 = *(const s16x8*)(Bp);
    s16x8 bf1 = *(const s16x8*)(Bp + 16 * ldb);
    s16x8 bf2 = *(const s16x8*)(Bp + 32 * ldb);
    s16x8 bf3 = *(const s16x8*)(Bp + 48 * ldb);
    Ap += 32; Bp += 32;
    acc[0][0] = mfma16(af0, bf0, acc[0][0]);
    acc[0][1] = mfma16(af0, bf1, acc[0][1]);
    acc[0][2] = mfma16(af0, bf2, acc[0][2]);
    acc[0][3] = mfma16(af0, bf3, acc[0][3]);
    acc[1][0] = mfma16(af1, bf0, acc[1][0]);
    acc[1][1] = mfma16(af1, bf1, acc[1][1]);
    acc[1][2] = mfma16(af1, bf2, acc[1][2]);
    acc[1][3] = mfma16(af1, bf3, acc[1][3]);
  }

  int rb = (lane >> 4) * 4;
  #pragma unroll
  for (int i = 0; i < 2; i++) {
    #pragma unroll
    for (int j = 0; j < 4; j++) {
      int col = n0 + j * 16 + lr;
      float bv = 0.f;
      if (BIAS) bv = bias[col];
      #pragma unroll
      for (int r = 0; r < 4; r++) {
        int row = m0 + i * 16 + rb + r;
        float v = acc[i][j][r] + bv;
        size_t idx = coff + (size_t)row * ldc + col;
        if (WF32) Cf[idx] = v;
        if (WB16) Cb[idx] = f2b(v);
      }
    }
  }
}

// ---------------------------------------------------------------------------
// v (f32, [n][l][h*64+d]) -> vt (bf16, [n*16+h][d][l])  via LDS tile
// grid: (L/64, N*H) blocks of 256
// ---------------------------------------------------------------------------
__global__ __launch_bounds__(256) void transpose_v_k(
    const float* __restrict__ vf, unsigned short* __restrict__ vt) {
  __shared__ unsigned short tile[64][72];   // 72*2=144B row stride (16B aligned)
  int nh = blockIdx.y, n = nh >> 4, h = nh & 15;
  int l0 = blockIdx.x * 64;
  int t = threadIdx.x;
  int lr = t >> 2;             // 0..63 : l within tile
  int dc = (t & 3) * 16;       // 0,16,32,48 : d chunk
  const float* src = vf + ((size_t)(n * 2048 + l0 + lr)) * 1024 + h * 64 + dc;
  float4 a = *(const float4*)(src);
  float4 b = *(const float4*)(src + 4);
  float4 c = *(const float4*)(src + 8);
  float4 e = *(const float4*)(src + 12);
  float vals[16] = {a.x, a.y, a.z, a.w, b.x, b.y, b.z, b.w,
                    c.x, c.y, c.z, c.w, e.x, e.y, e.z, e.w};
  #pragma unroll
  for (int j = 0; j < 16; j++) tile[dc + j][lr] = f2b(vals[j]);
  __syncthreads();
  int dr = t >> 2;             // d row
  int lc = (t & 3) * 16;       // l chunk
  unsigned short* dst = vt + ((size_t)nh * 64 + dr) * 2048 + l0 + lc;
  *(u16x8*)(dst)     = *(const u16x8*)&tile[dr][lc];
  *(u16x8*)(dst + 8) = *(const u16x8*)&tile[dr][lc + 8];
}

// ---------------------------------------------------------------------------
// Row softmax: attention[r][:] = softmax(energy[r][:] * 0.125), rows of 2048
// One block (256 thr) per row; whole row in registers (8 f32/thread).
// ---------------------------------------------------------------------------
__global__ __launch_bounds__(256) void softmax_rows(
    const float* __restrict__ e, float* __restrict__ p) {
  __shared__ float red[4];
  size_t r = blockIdx.x;
  const float* src = e + r * 2048;
  float* dst = p + r * 2048;
  int t = threadIdx.x, lane = t & 63, w = t >> 6;
  float4 x0 = *(const float4*)(src + t * 4);
  float4 x1 = *(const float4*)(src + 1024 + t * 4);

  float m = fmaxf(fmaxf(fmaxf(x0.x, x0.y), fmaxf(x0.z, x0.w)),
                  fmaxf(fmaxf(x1.x, x1.y), fmaxf(x1.z, x1.w)));
  #pragma unroll
  for (int off = 32; off; off >>= 1) m = fmaxf(m, __shfl_xor(m, off));
  if (lane == 0) red[w] = m;
  __syncthreads();
  float M = fmaxf(fmaxf(red[0], red[1]), fmaxf(red[2], red[3]));

  const float sc = 0.125f;
  float ev[8];
  ev[0] = __expf((x0.x - M) * sc); ev[1] = __expf((x0.y - M) * sc);
  ev[2] = __expf((x0.z - M) * sc); ev[3] = __expf((x0.w - M) * sc);
  ev[4] = __expf((x1.x - M) * sc); ev[5] = __expf((x1.y - M) * sc);
  ev[6] = __expf((x1.z - M) * sc); ev[7] = __expf((x1.w - M) * sc);
  float s = ev[0] + ev[1] + ev[2] + ev[3] + ev[4] + ev[5] + ev[6] + ev[7];
  #pragma unroll
  for (int off = 32; off; off >>= 1) s += __shfl_xor(s, off);
  __syncthreads();                 // red[0..3] reads (for M) complete
  if (lane == 0) red[w] = s;
  __syncthreads();
  float inv = 1.0f / (red[0] + red[1] + red[2] + red[3]);

  float4 o0, o1;
  o0.x = ev[0] * inv; o0.y = ev[1] * inv; o0.z = ev[2] * inv; o0.w = ev[3] * inv;
  o1.x = ev[4] * inv; o1.y = ev[5] * inv; o1.z = ev[6] * inv; o1.w = ev[7] * inv;
  *(float4*)(dst + t * 4) = o0;
  *(float4*)(dst + 1024 + t * 4) = o1;
}

// ---------------------------------------------------------------------------
// PV: head[n][q][h][d] = sum_l attention[nh][q][l] * v[n][l][h][d]
// A = attention f32 (cvt inline), B = vt bf16 [nh][d][l] (contig fragments).
// Block: 4 waves, each wave 16 q-rows x 64 d; grid (L/64, N*H).
// ---------------------------------------------------------------------------
__global__ __launch_bounds__(256) void pv_k(
    const float* __restrict__ attn, const unsigned short* __restrict__ vt,
    unsigned short* __restrict__ head) {
  int nh = blockIdx.y, n = nh >> 4, h = nh & 15;
  const float* A = attn + (size_t)nh * (2048ull * 2048ull);
  const unsigned short* Bv = vt + (size_t)nh * (64ull * 2048ull);
  int t = threadIdx.x, w = t >> 6, lane = t & 63;
  int lr = lane & 15, kg = (lane >> 4) * 8;
  int arow = blockIdx.x * 64 + w * 16 + lr;

  f32x4 acc[4] = {};
  const float* ap = A + (size_t)arow * 2048 + kg;
  const unsigned short* bp = Bv + (size_t)lr * 2048 + kg;

  for (int k0 = 0; k0 < 2048; k0 += 32) {
    float4 a0 = *(const float4*)(ap);
    float4 a1 = *(const float4*)(ap + 4);
    s16x8 af = pack8(a0, a1);
    #pragma unroll
    for (int j = 0; j < 4; j++) {
      s16x8 bf = *(const s16x8*)(bp + (size_t)j * 16 * 2048);
      acc[j] = mfma16(af, bf, acc[j]);
    }
    ap += 32; bp += 32;
  }

  int rb = (lane >> 4) * 4;
  #pragma unroll
  for (int j = 0; j < 4; j++) {
    #pragma unroll
    for (int r = 0; r < 4; r++) {
      int qrow = blockIdx.x * 64 + w * 16 + rb + r;
      int col = j * 16 + lr;
      head[((size_t)(n * 2048 + qrow)) * 1024 + h * 64 + col] = f2b(acc[j][r]);
    }
  }
}

// ---------------------------------------------------------------------------
extern "C" void kernel_launch(void* const* d_in, const int* in_sizes, int n_in,
                              void* d_out, int out_size, void* d_ws, size_t ws_size,
                              hipStream_t stream) {
  const float* Vin = (const float*)d_in[0];
  const float* Kin = (const float*)d_in[1];
  const float* Qin = (const float*)d_in[2];
  const float* Wq  = (const float*)d_in[3];
  const float* bq  = (const float*)d_in[4];
  const float* Wk  = (const float*)d_in[5];
  const float* bk  = (const float*)d_in[6];
  const float* Wv  = (const float*)d_in[7];
  const float* bv  = (const float*)d_in[8];
  const float* Wo  = (const float*)d_in[9];
  const float* bo  = (const float*)d_in[10];

  float* out    = (float*)d_out;
  float* qf     = out + 4194304;          // (2,2048,16,64) == (4096,1024)
  float* kf     = out + 8388608;
  float* vf     = out + 12582912;
  float* energy = out + 16777216;         // (2,16,2048,2048)
  float* attn   = out + 150994944;

  // scratch carved from dead d_out regions:
  unsigned short* xq  = (unsigned short*)energy;          // bf16 inputs/weights
  unsigned short* xk  = xq + 4194304;
  unsigned short* xv  = xk + 4194304;
  unsigned short* wqb = xv + 4194304;
  unsigned short* wkb = wqb + 1048576;
  unsigned short* wvb = wkb + 1048576;
  unsigned short* qb  = (unsigned short*)attn;            // bf16 q,k
  unsigned short* kb  = qb + 4194304;
  unsigned short* vt  = (unsigned short*)out;             // bf16 v^T (out region)
  // true workspace (10.5 MB):
  unsigned short* head = (unsigned short*)d_ws;           // bf16 head_out
  unsigned short* wob  = head + 4194304;                  // bf16 Wo

  const long long LDA = 1024, LDE = 2048;
  const long long SQn = 2048LL * 1024, SQh = 64;          // q/k slice strides
  const long long SEz = 2048LL * 2048;

  // 1) convert
  f32_to_bf16_k<<<4096, 256, 0, stream>>>(Qin, xq, 4194304);
  f32_to_bf16_k<<<4096, 256, 0, stream>>>(Kin, xk, 4194304);
  f32_to_bf16_k<<<4096, 256, 0, stream>>>(Vin, xv, 4194304);
  f32_to_bf16_k<<<1024, 256, 0, stream>>>(Wq, wqb, 1048576);
  f32_to_bf16_k<<<1024, 256, 0, stream>>>(Wk, wkb, 1048576);
  f32_to_bf16_k<<<1024, 256, 0, stream>>>(Wv, wvb, 1048576);
  f32_to_bf16_k<<<1024, 256, 0, stream>>>(Wo, wob, 1048576);

  // 2) projections: q,k write f32 + bf16; v writes f32 only
  gemm_nt<true, true, true><<<dim3(8, 64, 1), 256, 0, stream>>>(
      xq, LDA, 0, 0, wqb, LDA, 0, 0, bq, qf, qb, LDA, 0, 1024);
  gemm_nt<true, true, true><<<dim3(8, 64, 1), 256, 0, stream>>>(
      xk, LDA, 0, 0, wkb, LDA, 0, 0, bk, kf, kb, LDA, 0, 1024);
  gemm_nt<true, true, false><<<dim3(8, 64, 1), 256, 0, stream>>>(
      xv, LDA, 0, 0, wvb, LDA, 0, 0, bv, vf, nullptr, LDA, 0, 1024);

  // 3) v^T bf16
  transpose_v_k<<<dim3(32, 32), 256, 0, stream>>>(vf, vt);

  // 4) energy: per-(n,h) 2048x2048, K=64
  gemm_nt<false, true, false><<<dim3(16, 32, 32), 256, 0, stream>>>(
      qb, LDA, SQn, SQh, kb, LDA, SQn, SQh, nullptr,
      energy, nullptr, LDE, SEz, 64);

  // 5) softmax over last axis (scale 1/8)
  softmax_rows<<<65536, 256, 0, stream>>>(energy, attn);

  // 6) PV -> head bf16
  pv_k<<<dim3(32, 32), 256, 0, stream>>>(attn, vt, head);

  // 7) out = head @ Wo^T + bo
  gemm_nt<true, true, false><<<dim3(8, 64, 1), 256, 0, stream>>>(
      head, LDA, 0, 0, wob, LDA, 0, 0, bo, out, nullptr, LDA, 0, 1024);
}